// Round 4
// baseline (378.138 us; speedup 1.0000x reference)
//
#include <hip/hip_runtime.h>
#include <math.h>

#define B_SZ 32
#define L_SZ 4096
#define H_SZ 512
#define S_SPLIT 32
#define CHUNK (L_SZ / S_SPLIT)        /* 128 rows per block */
#define ROWS_PER_WAVE (CHUNK / 4)     /* 32 rows per wave   */
#define RBATCH 4                      /* rows per online-softmax block update */

// Pass 1: flash-style online softmax + mix accumulation, single pass over context.
// Each wave owns ROWS_PER_WAVE consecutive rows; lane i owns h = {4i..4i+3, 256+4i..256+4i+3}.
// Rows are processed RBATCH at a time: batched loads -> independent dots ->
// interleaved shuffle reduces -> ONE accumulator rescale per group.
__global__ __launch_bounds__(256, 4)
void attn_pass1(const float* __restrict__ q,        // [B,H]
                const float* __restrict__ ctx,      // [B,L,H]
                float* __restrict__ scores_out,     // [B,L]  (raw scores -> attn slot of d_out)
                float* __restrict__ m_part,         // [B,S]
                float* __restrict__ s_part,         // [B,S]
                float* __restrict__ acc_part)       // [B,S,H]
{
    const int bid   = blockIdx.x;
    const int b     = bid / S_SPLIT;
    const int split = bid % S_SPLIT;
    const int tid   = threadIdx.x;
    const int wave  = tid >> 6;
    const int lane  = tid & 63;

    float qr[8];
    {
        const float4* qv = (const float4*)(q + (size_t)b * H_SZ);
        const float4 q0 = qv[lane];
        const float4 q1 = qv[64 + lane];
        qr[0]=q0.x; qr[1]=q0.y; qr[2]=q0.z; qr[3]=q0.w;
        qr[4]=q1.x; qr[5]=q1.y; qr[6]=q1.z; qr[7]=q1.w;
    }

    float m = -INFINITY;
    float s = 0.f;
    float acc[8] = {0.f,0.f,0.f,0.f,0.f,0.f,0.f,0.f};
    float sc_keep = 0.f;   // ROWS_PER_WAVE==32: lane i keeps row i's score

    const int l0 = split * CHUNK + wave * ROWS_PER_WAVE;
    const float* ctx_b = ctx + (size_t)b * L_SZ * H_SZ;

    #pragma unroll 2
    for (int i0 = 0; i0 < ROWS_PER_WAVE; i0 += RBATCH) {
        float cr[RBATCH][8];
        #pragma unroll
        for (int j = 0; j < RBATCH; ++j) {
            const float4* cv = (const float4*)(ctx_b + (size_t)(l0 + i0 + j) * H_SZ);
            const float4 c0 = cv[lane];
            const float4 c1 = cv[64 + lane];
            cr[j][0]=c0.x; cr[j][1]=c0.y; cr[j][2]=c0.z; cr[j][3]=c0.w;
            cr[j][4]=c1.x; cr[j][5]=c1.y; cr[j][6]=c1.z; cr[j][7]=c1.w;
        }

        // 4 independent partial dots
        float p[RBATCH];
        #pragma unroll
        for (int j = 0; j < RBATCH; ++j) {
            float acc_p = 0.f;
            #pragma unroll
            for (int k = 0; k < 8; ++k) acc_p += qr[k] * cr[j][k];
            p[j] = acc_p;
        }

        // interleaved butterfly reduces (independent chains pipeline)
        #pragma unroll
        for (int off = 32; off >= 1; off >>= 1) {
            #pragma unroll
            for (int j = 0; j < RBATCH; ++j)
                p[j] += __shfl_xor(p[j], off, 64);
        }

        // lane (i0+j) keeps row (i0+j)'s raw score for the coalesced store
        #pragma unroll
        for (int j = 0; j < RBATCH; ++j)
            if (lane == i0 + j) sc_keep = p[j];

        // block online-softmax update; sc==0 means masked (-inf in reference)
        float mx = m;
        #pragma unroll
        for (int j = 0; j < RBATCH; ++j)
            if (p[j] != 0.f) mx = fmaxf(mx, p[j]);

        if (mx > -INFINITY) {
            const float corr = __expf(m - mx);      // exp(-inf)=0 on first valid group
            float pw[RBATCH];
            float psum = 0.f;
            #pragma unroll
            for (int j = 0; j < RBATCH; ++j) {
                pw[j] = (p[j] != 0.f) ? __expf(p[j] - mx) : 0.f;
                psum += pw[j];
            }
            s = s * corr + psum;
            #pragma unroll
            for (int k = 0; k < 8; ++k) {
                float a = acc[k] * corr;
                #pragma unroll
                for (int j = 0; j < RBATCH; ++j)
                    a += pw[j] * cr[j][k];
                acc[k] = a;
            }
            m = mx;
        }
    }

    // coalesced raw-score store: lanes 0..31 hold rows l0..l0+31
    if (lane < ROWS_PER_WAVE)
        scores_out[(size_t)b * L_SZ + l0 + lane] = sc_keep;

    // combine 4 waves -> one block partial
    __shared__ float lds_m[4];
    __shared__ float lds_s[4];
    __shared__ float lds_acc[4][H_SZ];
    if (lane == 0) { lds_m[wave] = m; lds_s[wave] = s; }
    float* la = lds_acc[wave];
    #pragma unroll
    for (int k = 0; k < 4; ++k) la[4 * lane + k]       = acc[k];
    #pragma unroll
    for (int k = 0; k < 4; ++k) la[256 + 4 * lane + k] = acc[4 + k];
    __syncthreads();

    const float mb = fmaxf(fmaxf(lds_m[0], lds_m[1]), fmaxf(lds_m[2], lds_m[3]));
    float sb = 0.f, ac0 = 0.f, ac1 = 0.f;
    #pragma unroll
    for (int w = 0; w < 4; ++w) {
        const float wg = (lds_s[w] > 0.f) ? __expf(lds_m[w] - mb) : 0.f;
        sb  += wg * lds_s[w];
        ac0 += wg * lds_acc[w][tid];
        ac1 += wg * lds_acc[w][tid + 256];
    }
    const int ps = b * S_SPLIT + split;
    if (tid == 0) { m_part[ps] = mb; s_part[ps] = sb; }
    acc_part[(size_t)ps * H_SZ + tid]       = ac0;
    acc_part[(size_t)ps * H_SZ + tid + 256] = ac1;
}

// Pass 2a (one block of 512 per batch): combine split partials -> normalized mix,
// finalize attn in-place (scores -> softmax weights).
__global__ __launch_bounds__(512)
void attn_combine(const float* __restrict__ m_part,
                  const float* __restrict__ s_part,
                  const float* __restrict__ acc_part,
                  float* __restrict__ mix_out,      // [B,H]
                  float* __restrict__ attn)         // [B,L] raw scores on entry
{
    const int b   = blockIdx.x;
    const int tid = threadIdx.x;   // 512 = H

    float m = -INFINITY;
    #pragma unroll
    for (int j = 0; j < S_SPLIT; ++j)
        m = fmaxf(m, m_part[b * S_SPLIT + j]);

    float stot = 0.f, mx = 0.f;
    #pragma unroll
    for (int j = 0; j < S_SPLIT; ++j) {
        const float sj = s_part[b * S_SPLIT + j];
        const float wg = (sj > 0.f) ? __expf(m_part[b * S_SPLIT + j] - m) : 0.f;
        stot += wg * sj;
        mx   += wg * acc_part[(size_t)(b * S_SPLIT + j) * H_SZ + tid];
    }
    const float inv = (stot > 0.f) ? 1.f / stot : 0.f;
    mix_out[(size_t)b * H_SZ + tid] = mx * inv;

    #pragma unroll
    for (int l = tid; l < L_SZ; l += 512) {
        const float sc = attn[(size_t)b * L_SZ + l];
        attn[(size_t)b * L_SZ + l] = (sc != 0.0f) ? __expf(sc - m) * inv : 0.f;
    }
}

// Pass 2b: out = tanh([mix, q] @ W^T + b). One WAVE per output element [b,h]:
// 64 lanes split the 1024-long dot, coalesced float4 W loads, shuffle reduce.
__global__ __launch_bounds__(256)
void attn_gemv(const float* __restrict__ q,         // [B,H]
               const float* __restrict__ W,         // [H, 2H]
               const float* __restrict__ bias,      // [H]
               const float* __restrict__ mix,       // [B,H]
               float* __restrict__ out)             // [B,H]
{
    const int wave = threadIdx.x >> 6;
    const int lane = threadIdx.x & 63;
    const int oi   = blockIdx.x * 4 + wave;     // 0 .. B*H-1
    const int b    = oi >> 9;                   // H = 512
    const int h    = oi & (H_SZ - 1);

    const float4* Wr = (const float4*)(W + (size_t)h * (2 * H_SZ));  // 256 float4
    const float4* mv = (const float4*)(mix + (size_t)b * H_SZ);      // 128 float4
    const float4* qv = (const float4*)(q   + (size_t)b * H_SZ);

    const float4 w0 = Wr[lane];
    const float4 w1 = Wr[64 + lane];
    const float4 w2 = Wr[128 + lane];
    const float4 w3 = Wr[192 + lane];
    const float4 x0 = mv[lane];
    const float4 x1 = mv[64 + lane];
    const float4 y0 = qv[lane];
    const float4 y1 = qv[64 + lane];

    float p = w0.x*x0.x + w0.y*x0.y + w0.z*x0.z + w0.w*x0.w
            + w1.x*x1.x + w1.y*x1.y + w1.z*x1.z + w1.w*x1.w
            + w2.x*y0.x + w2.y*y0.y + w2.z*y0.z + w2.w*y0.w
            + w3.x*y1.x + w3.y*y1.y + w3.z*y1.z + w3.w*y1.w;
    #pragma unroll
    for (int off = 32; off >= 1; off >>= 1)
        p += __shfl_xor(p, off, 64);

    if (lane == 0)
        out[oi] = tanhf(p + bias[h]);
}

extern "C" void kernel_launch(void* const* d_in, const int* in_sizes, int n_in,
                              void* d_out, int out_size, void* d_ws, size_t ws_size,
                              hipStream_t stream) {
    const float* q    = (const float*)d_in[0];   // output [B,H]
    const float* ctx  = (const float*)d_in[1];   // context [B,L,H]
    const float* W    = (const float*)d_in[2];   // [H, 2H]
    const float* bias = (const float*)d_in[3];   // [H]

    float* out  = (float*)d_out;                 // [B,H] first
    float* attn = out + B_SZ * H_SZ;             // [B,1,L] second (scores scratch -> attn)

    float* ws       = (float*)d_ws;
    float* m_part   = ws;                                       // B*S
    float* s_part   = ws + B_SZ * S_SPLIT;                      // B*S
    float* acc_part = ws + 2 * B_SZ * S_SPLIT;                  // B*S*H (~2 MiB)
    float* mix      = acc_part + (size_t)B_SZ * S_SPLIT * H_SZ; // B*H

    attn_pass1<<<B_SZ * S_SPLIT, 256, 0, stream>>>(q, ctx, attn, m_part, s_part, acc_part);
    attn_combine<<<B_SZ, 512, 0, stream>>>(m_part, s_part, acc_part, mix, attn);
    attn_gemv<<<(B_SZ * H_SZ) / 4, 256, 0, stream>>>(q, W, bias, mix, out);
}